// Round 4
// baseline (610.397 us; speedup 1.0000x reference)
//
#include <hip/hip_runtime.h>
#include <math.h>
#include <stdint.h>

#define N_NODES 50000
#define N_EDGES 800000
#define IN_FEATS 128
#define HIDDEN 64
#define SCAN_BLK 256
#define SCAN_ELEMS 1024  // 4 per thread

// --- integer degree histogram ---
__global__ __launch_bounds__(256) void deg_kernel(const int* __restrict__ src,
                                                  const int* __restrict__ dst,
                                                  int* __restrict__ deg_out,
                                                  int* __restrict__ deg_in) {
    int e = blockIdx.x * 256 + threadIdx.x;
    if (e < N_EDGES) {
        atomicAdd(&deg_out[src[e]], 1);
        atomicAdd(&deg_in[dst[e]], 1);
    }
}

// --- c = 1/sqrt(max(deg,1)) ---
__global__ __launch_bounds__(256) void cnorm_kernel(const int* __restrict__ dout,
                                                    const int* __restrict__ din,
                                                    float* __restrict__ cs,
                                                    float* __restrict__ cd) {
    int v = blockIdx.x * 256 + threadIdx.x;
    if (v < N_NODES) {
        cs[v] = rsqrtf(fmaxf((float)dout[v], 1.0f));
        cd[v] = rsqrtf(fmaxf((float)din[v], 1.0f));
    }
}

// --- scan stage 1: per-block exclusive scan of 1024 elements, emit block sums ---
__global__ __launch_bounds__(SCAN_BLK) void scan1_kernel(const int* __restrict__ deg,
                                                         int* __restrict__ offs,
                                                         int* __restrict__ bsum) {
    __shared__ int sums[SCAN_BLK];
    int t = threadIdx.x;
    int base = blockIdx.x * SCAN_ELEMS + t * 4;
    int d0 = (base + 0 < N_NODES) ? deg[base + 0] : 0;
    int d1 = (base + 1 < N_NODES) ? deg[base + 1] : 0;
    int d2 = (base + 2 < N_NODES) ? deg[base + 2] : 0;
    int d3 = (base + 3 < N_NODES) ? deg[base + 3] : 0;
    sums[t] = d0 + d1 + d2 + d3;
    __syncthreads();
    for (int o = 1; o < SCAN_BLK; o <<= 1) {
        int v = (t >= o) ? sums[t - o] : 0;
        __syncthreads();
        sums[t] += v;
        __syncthreads();
    }
    int excl = (t == 0) ? 0 : sums[t - 1];
    if (base + 0 < N_NODES) offs[base + 0] = excl;
    if (base + 1 < N_NODES) offs[base + 1] = excl + d0;
    if (base + 2 < N_NODES) offs[base + 2] = excl + d0 + d1;
    if (base + 3 < N_NODES) offs[base + 3] = excl + d0 + d1 + d2;
    if (t == SCAN_BLK - 1) bsum[blockIdx.x] = sums[SCAN_BLK - 1];
}

// --- scan stage 2: single wave exclusive scan of block sums (nb <= 64) ---
__global__ __launch_bounds__(64) void scan2_kernel(int* __restrict__ bsum, int nb) {
    int t = threadIdx.x;
    int v = (t < nb) ? bsum[t] : 0;
    int s = v;
#pragma unroll
    for (int o = 1; o < 64; o <<= 1) {
        int u = __shfl_up(s, o, 64);
        if (t >= o) s += u;
    }
    if (t < nb) bsum[t] = s - v;  // exclusive
}

// --- scan stage 3: add block offsets ---
__global__ __launch_bounds__(256) void scan3_kernel(int* __restrict__ offs,
                                                    const int* __restrict__ bsum) {
    int i = blockIdx.x * 256 + threadIdx.x;
    if (i < N_NODES) offs[i] += bsum[i >> 10];  // SCAN_ELEMS = 1024
    if (i == 0) offs[N_NODES] = N_EDGES;        // every dst < N, total = N_EDGES
}

// --- fill CSR: csr_src[offs[dst]+k] = src ---
__global__ __launch_bounds__(256) void bucket_kernel(const int* __restrict__ src,
                                                     const int* __restrict__ dst,
                                                     const int* __restrict__ offs,
                                                     int* __restrict__ cnt,
                                                     int* __restrict__ csr_src) {
    int e = blockIdx.x * 256 + threadIdx.x;
    if (e >= N_EDGES) return;
    int d = dst[e];
    int pos = atomicAdd(&cnt[d], 1);
    csr_src[offs[d] + pos] = src[e];
}

// --- y[v,:] = c_src[v] * (h[v,:] @ W) ---
// LDS-tiled: 32-row x tile staged coalesced; W as float4 per (k-quad, col).
// 256 thr = 4 waves; wave w computes rows [tile + 8w, tile + 8w + 8), col = lane.
template <int K>
__global__ __launch_bounds__(256) void gemm_scaled_kernel(const float* __restrict__ h,
                                                          const float* __restrict__ c_src,
                                                          const float* __restrict__ W,
                                                          float* __restrict__ y) {
    constexpr int KQ = K / 4;  // float4s per row
    __shared__ float4 Ws4[KQ * HIDDEN];
    __shared__ float4 Xs[32 * KQ];
    for (int idx = threadIdx.x; idx < KQ * HIDDEN; idx += 256) {
        int k4 = idx >> 6, col = idx & 63;
        Ws4[idx] = make_float4(W[(4 * k4 + 0) * HIDDEN + col], W[(4 * k4 + 1) * HIDDEN + col],
                               W[(4 * k4 + 2) * HIDDEN + col], W[(4 * k4 + 3) * HIDDEN + col]);
    }
    int wid = threadIdx.x >> 6, lane = threadIdx.x & 63;
    for (int base = blockIdx.x * 32; base < N_NODES; base += gridDim.x * 32) {
        int nrows = min(32, N_NODES - base);
        __syncthreads();  // Xs reuse + (first iter) W ready
        const float4* src4 = reinterpret_cast<const float4*>(h + (size_t)base * K);
        for (int idx = threadIdx.x; idx < nrows * KQ; idx += 256) Xs[idx] = src4[idx];
        __syncthreads();
        int r0 = wid * 8;
        if (base + r0 >= N_NODES) continue;
        float acc[8] = {0.f, 0.f, 0.f, 0.f, 0.f, 0.f, 0.f, 0.f};
#pragma unroll
        for (int k4 = 0; k4 < KQ; ++k4) {
            float4 w = Ws4[k4 * 64 + lane];
#pragma unroll
            for (int r = 0; r < 8; ++r) {
                float4 a = Xs[(r0 + r) * KQ + k4];
                acc[r] = fmaf(a.x, w.x, fmaf(a.y, w.y, fmaf(a.z, w.z, fmaf(a.w, w.w, acc[r]))));
            }
        }
#pragma unroll
        for (int r = 0; r < 8; ++r) {
            int row = base + r0 + r;
            if (row < N_NODES) y[(size_t)row * HIDDEN + lane] = acc[r] * c_src[row];
        }
    }
}

// --- layer1 aggregate: 4 edges/iter per wave (4 slots x 16 lanes x float4) + bias/relu ---
__global__ __launch_bounds__(256) void gather_relu_kernel(const float* __restrict__ y,
                                                          const int* __restrict__ offs,
                                                          const int* __restrict__ csr_src,
                                                          const float* __restrict__ c_dst,
                                                          const float* __restrict__ b1,
                                                          float* __restrict__ h) {
    int wid = threadIdx.x >> 6, l = threadIdx.x & 63;
    int g = l >> 4, q = l & 15;
    int v = blockIdx.x * 4 + wid;  // grid exact: 12500 * 4 = 50000
    int beg = offs[v], end = offs[v + 1];
    float4 acc = make_float4(0.f, 0.f, 0.f, 0.f);
    int k = beg;
    for (; k + 4 <= end; k += 4) {
        int s = csr_src[k + g];
        float4 vy = *reinterpret_cast<const float4*>(y + (long)s * HIDDEN + q * 4);
        acc.x += vy.x; acc.y += vy.y; acc.z += vy.z; acc.w += vy.w;
    }
    int rem = end - k;
    if (g < rem) {
        int s = csr_src[k + g];
        float4 vy = *reinterpret_cast<const float4*>(y + (long)s * HIDDEN + q * 4);
        acc.x += vy.x; acc.y += vy.y; acc.z += vy.z; acc.w += vy.w;
    }
    // combine the 4 slots: lanes {q, q+16, q+32, q+48}
    acc.x += __shfl_xor(acc.x, 16, 64); acc.y += __shfl_xor(acc.y, 16, 64);
    acc.z += __shfl_xor(acc.z, 16, 64); acc.w += __shfl_xor(acc.w, 16, 64);
    acc.x += __shfl_xor(acc.x, 32, 64); acc.y += __shfl_xor(acc.y, 32, 64);
    acc.z += __shfl_xor(acc.z, 32, 64); acc.w += __shfl_xor(acc.w, 32, 64);
    if (g == 0) {
        float c = c_dst[v];
        float4 b = *reinterpret_cast<const float4*>(b1 + q * 4);
        float4 r;
        r.x = fmaxf(fmaf(c, acc.x, b.x), 0.f);
        r.y = fmaxf(fmaf(c, acc.y, b.y), 0.f);
        r.z = fmaxf(fmaf(c, acc.z, b.z), 0.f);
        r.w = fmaxf(fmaf(c, acc.w, b.w), 0.f);
        *reinterpret_cast<float4*>(h + (long)v * HIDDEN + q * 4) = r;
    }
}

// --- layer2 aggregate + bias + We dot-products -> a_s, a_d ---
__global__ __launch_bounds__(256) void gather_logit_kernel(const float* __restrict__ y,
                                                           const int* __restrict__ offs,
                                                           const int* __restrict__ csr_src,
                                                           const float* __restrict__ c_dst,
                                                           const float* __restrict__ b2,
                                                           const float* __restrict__ We,
                                                           float* __restrict__ a_s,
                                                           float* __restrict__ a_d) {
    int wid = threadIdx.x >> 6, l = threadIdx.x & 63;
    int g = l >> 4, q = l & 15;
    int v = blockIdx.x * 4 + wid;
    int beg = offs[v], end = offs[v + 1];
    float4 acc = make_float4(0.f, 0.f, 0.f, 0.f);
    int k = beg;
    for (; k + 4 <= end; k += 4) {
        int s = csr_src[k + g];
        float4 vy = *reinterpret_cast<const float4*>(y + (long)s * HIDDEN + q * 4);
        acc.x += vy.x; acc.y += vy.y; acc.z += vy.z; acc.w += vy.w;
    }
    int rem = end - k;
    if (g < rem) {
        int s = csr_src[k + g];
        float4 vy = *reinterpret_cast<const float4*>(y + (long)s * HIDDEN + q * 4);
        acc.x += vy.x; acc.y += vy.y; acc.z += vy.z; acc.w += vy.w;
    }
    acc.x += __shfl_xor(acc.x, 16, 64); acc.y += __shfl_xor(acc.y, 16, 64);
    acc.z += __shfl_xor(acc.z, 16, 64); acc.w += __shfl_xor(acc.w, 16, 64);
    acc.x += __shfl_xor(acc.x, 32, 64); acc.y += __shfl_xor(acc.y, 32, 64);
    acc.z += __shfl_xor(acc.z, 32, 64); acc.w += __shfl_xor(acc.w, 32, 64);
    float c = c_dst[v];
    float4 b = *reinterpret_cast<const float4*>(b2 + q * 4);
    float4 ws = *reinterpret_cast<const float4*>(We + q * 4);
    float4 wd = *reinterpret_cast<const float4*>(We + HIDDEN + q * 4);
    float hx = fmaf(c, acc.x, b.x), hy = fmaf(c, acc.y, b.y);
    float hz = fmaf(c, acc.z, b.z), hw = fmaf(c, acc.w, b.w);
    float ps = hx * ws.x + hy * ws.y + hz * ws.z + hw * ws.w;
    float pd = hx * wd.x + hy * wd.y + hz * wd.z + hw * wd.w;
    // reduce within 16-lane group (garbage in slots g>0 never crosses in)
#pragma unroll
    for (int o = 1; o <= 8; o <<= 1) {
        ps += __shfl_xor(ps, o, 64);
        pd += __shfl_xor(pd, o, 64);
    }
    if (l == 0) {
        a_s[v] = ps;
        a_d[v] = pd;
    }
}

// --- out[e] = sigmoid(a_s[src] + a_d[dst] + efeat.Wf + be) ---
__global__ __launch_bounds__(256) void edge_out_kernel(const int* __restrict__ src,
                                                       const int* __restrict__ dst,
                                                       const float* __restrict__ efeat,
                                                       const float* __restrict__ We,
                                                       const float* __restrict__ be,
                                                       const float* __restrict__ a_s,
                                                       const float* __restrict__ a_d,
                                                       float* __restrict__ out) {
    int e = blockIdx.x * 256 + threadIdx.x;
    if (e >= N_EDGES) return;
    float logit = a_s[src[e]] + a_d[dst[e]]
                + efeat[(long)e * 3 + 0] * We[2 * HIDDEN + 0]
                + efeat[(long)e * 3 + 1] * We[2 * HIDDEN + 1]
                + efeat[(long)e * 3 + 2] * We[2 * HIDDEN + 2]
                + be[0];
    out[e] = 1.0f / (1.0f + expf(-logit));
}

extern "C" void kernel_launch(void* const* d_in, const int* in_sizes, int n_in,
                              void* d_out, int out_size, void* d_ws, size_t ws_size,
                              hipStream_t stream) {
    const float* x     = (const float*)d_in[0];
    const float* efeat = (const float*)d_in[1];
    const int*   src   = (const int*)d_in[2];
    const int*   dst   = (const int*)d_in[3];
    const float* W1    = (const float*)d_in[4];
    const float* b1    = (const float*)d_in[5];
    const float* W2    = (const float*)d_in[6];
    const float* b2    = (const float*)d_in[7];
    const float* We    = (const float*)d_in[8];
    const float* be    = (const float*)d_in[9];
    float* out = (float*)d_out;

    // 256B-aligned workspace carve-up (float4 paths require 16B alignment)
    char* p = (char*)d_ws;
    auto alloc = [&](size_t bytes) {
        char* r = p;
        p += (bytes + 255) & ~(size_t)255;
        return r;
    };
    float* c_src   = (float*)alloc((size_t)N_NODES * 4);
    float* c_dst   = (float*)alloc((size_t)N_NODES * 4);
    float* a_s     = (float*)alloc((size_t)N_NODES * 4);
    float* a_d     = (float*)alloc((size_t)N_NODES * 4);
    int*   degs    = (int*)alloc((size_t)3 * N_NODES * 4);  // deg_out | deg_in | cnt
    int*   offs    = (int*)alloc((size_t)(N_NODES + 1) * 4);
    int*   bsum    = (int*)alloc(64 * 4);
    int*   csr_src = (int*)alloc((size_t)N_EDGES * 4);
    float* bufA    = (float*)alloc((size_t)N_NODES * HIDDEN * 4);
    float* bufB    = (float*)alloc((size_t)N_NODES * HIDDEN * 4);
    int* deg_out = degs;
    int* deg_in  = degs + N_NODES;
    int* cnt     = degs + 2 * N_NODES;

    const int NB_SCAN = (N_NODES + SCAN_ELEMS - 1) / SCAN_ELEMS;  // 49

    // degrees -> c_src/c_dst ; CSR build
    hipMemsetAsync(degs, 0, (size_t)3 * N_NODES * 4, stream);
    deg_kernel<<<N_EDGES / 256, 256, 0, stream>>>(src, dst, deg_out, deg_in);
    cnorm_kernel<<<(N_NODES + 255) / 256, 256, 0, stream>>>(deg_out, deg_in, c_src, c_dst);
    scan1_kernel<<<NB_SCAN, SCAN_BLK, 0, stream>>>(deg_in, offs, bsum);
    scan2_kernel<<<1, 64, 0, stream>>>(bsum, NB_SCAN);
    scan3_kernel<<<(N_NODES + 255) / 256, 256, 0, stream>>>(offs, bsum);
    bucket_kernel<<<N_EDGES / 256, 256, 0, stream>>>(src, dst, offs, cnt, csr_src);

    // layer 1: y1 = (x*c_src)@W1 ; h1 = relu(c_dst * gather + b1)
    const int NT1 = (N_NODES + 31) / 32;  // 1563 tiles
    gemm_scaled_kernel<IN_FEATS><<<NT1, 256, 0, stream>>>(x, c_src, W1, bufA);
    gather_relu_kernel<<<N_NODES / 4, 256, 0, stream>>>(bufA, offs, csr_src, c_dst, b1, bufB);

    // layer 2: y2 = (h1*c_src)@W2 ; fused gather + bias + We-dot -> a_s/a_d
    gemm_scaled_kernel<HIDDEN><<<NT1, 256, 0, stream>>>(bufB, c_src, W2, bufA);
    gather_logit_kernel<<<N_NODES / 4, 256, 0, stream>>>(bufA, offs, csr_src, c_dst, b2, We, a_s, a_d);

    // edge output
    edge_out_kernel<<<N_EDGES / 256, 256, 0, stream>>>(src, dst, efeat, We, be, a_s, a_d, out);
}

// Round 5
// 247.855 us; speedup vs baseline: 2.4627x; 2.4627x over previous
//
#include <hip/hip_runtime.h>
#include <math.h>
#include <stdint.h>

#define N_NODES 50000
#define N_EDGES 800000
#define IN_FEATS 128
#define HIDDEN 64
#define SCAN_BLK 256
#define SCAN_ELEMS 1024  // 4 per thread

// --- integer degree histogram ---
__global__ __launch_bounds__(256) void deg_kernel(const int* __restrict__ src,
                                                  const int* __restrict__ dst,
                                                  int* __restrict__ deg_out,
                                                  int* __restrict__ deg_in) {
    int e = blockIdx.x * 256 + threadIdx.x;
    if (e < N_EDGES) {
        atomicAdd(&deg_out[src[e]], 1);
        atomicAdd(&deg_in[dst[e]], 1);
    }
}

// --- c = 1/sqrt(max(deg,1)) ---
__global__ __launch_bounds__(256) void cnorm_kernel(const int* __restrict__ dout,
                                                    const int* __restrict__ din,
                                                    float* __restrict__ cs,
                                                    float* __restrict__ cd) {
    int v = blockIdx.x * 256 + threadIdx.x;
    if (v < N_NODES) {
        cs[v] = rsqrtf(fmaxf((float)dout[v], 1.0f));
        cd[v] = rsqrtf(fmaxf((float)din[v], 1.0f));
    }
}

// --- scan stage 1: per-block exclusive scan of 1024 elements, emit block sums ---
__global__ __launch_bounds__(SCAN_BLK) void scan1_kernel(const int* __restrict__ deg,
                                                         int* __restrict__ offs,
                                                         int* __restrict__ bsum) {
    __shared__ int sums[SCAN_BLK];
    int t = threadIdx.x;
    int base = blockIdx.x * SCAN_ELEMS + t * 4;
    int d0 = (base + 0 < N_NODES) ? deg[base + 0] : 0;
    int d1 = (base + 1 < N_NODES) ? deg[base + 1] : 0;
    int d2 = (base + 2 < N_NODES) ? deg[base + 2] : 0;
    int d3 = (base + 3 < N_NODES) ? deg[base + 3] : 0;
    sums[t] = d0 + d1 + d2 + d3;
    __syncthreads();
    for (int o = 1; o < SCAN_BLK; o <<= 1) {
        int v = (t >= o) ? sums[t - o] : 0;
        __syncthreads();
        sums[t] += v;
        __syncthreads();
    }
    int excl = (t == 0) ? 0 : sums[t - 1];
    if (base + 0 < N_NODES) offs[base + 0] = excl;
    if (base + 1 < N_NODES) offs[base + 1] = excl + d0;
    if (base + 2 < N_NODES) offs[base + 2] = excl + d0 + d1;
    if (base + 3 < N_NODES) offs[base + 3] = excl + d0 + d1 + d2;
    if (t == SCAN_BLK - 1) bsum[blockIdx.x] = sums[SCAN_BLK - 1];
}

// --- scan stage 2: single wave exclusive scan of block sums (nb <= 64) ---
__global__ __launch_bounds__(64) void scan2_kernel(int* __restrict__ bsum, int nb) {
    int t = threadIdx.x;
    int v = (t < nb) ? bsum[t] : 0;
    int s = v;
#pragma unroll
    for (int o = 1; o < 64; o <<= 1) {
        int u = __shfl_up(s, o, 64);
        if (t >= o) s += u;
    }
    if (t < nb) bsum[t] = s - v;  // exclusive
}

// --- scan stage 3: add block offsets ---
__global__ __launch_bounds__(256) void scan3_kernel(int* __restrict__ offs,
                                                    const int* __restrict__ bsum) {
    int i = blockIdx.x * 256 + threadIdx.x;
    if (i < N_NODES) offs[i] += bsum[i >> 10];  // SCAN_ELEMS = 1024
    if (i == 0) offs[N_NODES] = N_EDGES;        // every dst < N, total = N_EDGES
}

// --- fill CSR: csr_src[offs[dst]+k] = src ---
__global__ __launch_bounds__(256) void bucket_kernel(const int* __restrict__ src,
                                                     const int* __restrict__ dst,
                                                     const int* __restrict__ offs,
                                                     int* __restrict__ cnt,
                                                     int* __restrict__ csr_src) {
    int e = blockIdx.x * 256 + threadIdx.x;
    if (e >= N_EDGES) return;
    int d = dst[e];
    int pos = atomicAdd(&cnt[d], 1);
    csr_src[offs[d] + pos] = src[e];
}

// --- y[v,:] = c_src[v] * (h[v,:] @ W) ---
// LDS-tiled: 32-row x tile staged coalesced; W as float4 per (k-quad, col).
// 256 thr = 4 waves; wave w computes rows [tile + 8w, tile + 8w + 8), col = lane.
// k4 loop unrolled only 2x to keep VGPR pressure low (full unroll spilled: VGPR=256,
// 800 MB scratch writes, 4x regression).
template <int K>
__global__ __launch_bounds__(256) void gemm_scaled_kernel(const float* __restrict__ h,
                                                          const float* __restrict__ c_src,
                                                          const float* __restrict__ W,
                                                          float* __restrict__ y) {
    constexpr int KQ = K / 4;  // float4s per row
    __shared__ float4 Ws4[KQ * HIDDEN];
    __shared__ float4 Xs[32 * KQ];
    for (int idx = threadIdx.x; idx < KQ * HIDDEN; idx += 256) {
        int k4 = idx >> 6, col = idx & 63;
        Ws4[idx] = make_float4(W[(4 * k4 + 0) * HIDDEN + col], W[(4 * k4 + 1) * HIDDEN + col],
                               W[(4 * k4 + 2) * HIDDEN + col], W[(4 * k4 + 3) * HIDDEN + col]);
    }
    int wid = threadIdx.x >> 6, lane = threadIdx.x & 63;
    for (int base = blockIdx.x * 32; base < N_NODES; base += gridDim.x * 32) {
        int nrows = min(32, N_NODES - base);
        __syncthreads();  // Xs reuse + (first iter) W ready
        const float4* src4 = reinterpret_cast<const float4*>(h + (size_t)base * K);
        for (int idx = threadIdx.x; idx < nrows * KQ; idx += 256) Xs[idx] = src4[idx];
        __syncthreads();
        int r0 = wid * 8;
        if (base + r0 >= N_NODES) continue;
        float acc[8] = {0.f, 0.f, 0.f, 0.f, 0.f, 0.f, 0.f, 0.f};
#pragma unroll 2
        for (int k4 = 0; k4 < KQ; ++k4) {
            float4 w = Ws4[k4 * 64 + lane];
#pragma unroll
            for (int r = 0; r < 8; ++r) {
                float4 a = Xs[(r0 + r) * KQ + k4];
                acc[r] = fmaf(a.x, w.x, fmaf(a.y, w.y, fmaf(a.z, w.z, fmaf(a.w, w.w, acc[r]))));
            }
        }
#pragma unroll
        for (int r = 0; r < 8; ++r) {
            int row = base + r0 + r;
            if (row < N_NODES) y[(size_t)row * HIDDEN + lane] = acc[r] * c_src[row];
        }
    }
}

// --- layer1 aggregate: 4 edges/iter per wave (4 slots x 16 lanes x float4) + bias/relu ---
__global__ __launch_bounds__(256) void gather_relu_kernel(const float* __restrict__ y,
                                                          const int* __restrict__ offs,
                                                          const int* __restrict__ csr_src,
                                                          const float* __restrict__ c_dst,
                                                          const float* __restrict__ b1,
                                                          float* __restrict__ h) {
    int wid = threadIdx.x >> 6, l = threadIdx.x & 63;
    int g = l >> 4, q = l & 15;
    int v = blockIdx.x * 4 + wid;  // grid exact: 12500 * 4 = 50000
    int beg = offs[v], end = offs[v + 1];
    float4 acc = make_float4(0.f, 0.f, 0.f, 0.f);
    int k = beg;
    for (; k + 4 <= end; k += 4) {
        int s = csr_src[k + g];
        float4 vy = *reinterpret_cast<const float4*>(y + (long)s * HIDDEN + q * 4);
        acc.x += vy.x; acc.y += vy.y; acc.z += vy.z; acc.w += vy.w;
    }
    int rem = end - k;
    if (g < rem) {
        int s = csr_src[k + g];
        float4 vy = *reinterpret_cast<const float4*>(y + (long)s * HIDDEN + q * 4);
        acc.x += vy.x; acc.y += vy.y; acc.z += vy.z; acc.w += vy.w;
    }
    // combine the 4 slots: lanes {q, q+16, q+32, q+48}
    acc.x += __shfl_xor(acc.x, 16, 64); acc.y += __shfl_xor(acc.y, 16, 64);
    acc.z += __shfl_xor(acc.z, 16, 64); acc.w += __shfl_xor(acc.w, 16, 64);
    acc.x += __shfl_xor(acc.x, 32, 64); acc.y += __shfl_xor(acc.y, 32, 64);
    acc.z += __shfl_xor(acc.z, 32, 64); acc.w += __shfl_xor(acc.w, 32, 64);
    if (g == 0) {
        float c = c_dst[v];
        float4 b = *reinterpret_cast<const float4*>(b1 + q * 4);
        float4 r;
        r.x = fmaxf(fmaf(c, acc.x, b.x), 0.f);
        r.y = fmaxf(fmaf(c, acc.y, b.y), 0.f);
        r.z = fmaxf(fmaf(c, acc.z, b.z), 0.f);
        r.w = fmaxf(fmaf(c, acc.w, b.w), 0.f);
        *reinterpret_cast<float4*>(h + (long)v * HIDDEN + q * 4) = r;
    }
}

// --- layer2 aggregate + bias + We dot-products -> a_s, a_d ---
__global__ __launch_bounds__(256) void gather_logit_kernel(const float* __restrict__ y,
                                                           const int* __restrict__ offs,
                                                           const int* __restrict__ csr_src,
                                                           const float* __restrict__ c_dst,
                                                           const float* __restrict__ b2,
                                                           const float* __restrict__ We,
                                                           float* __restrict__ a_s,
                                                           float* __restrict__ a_d) {
    int wid = threadIdx.x >> 6, l = threadIdx.x & 63;
    int g = l >> 4, q = l & 15;
    int v = blockIdx.x * 4 + wid;
    int beg = offs[v], end = offs[v + 1];
    float4 acc = make_float4(0.f, 0.f, 0.f, 0.f);
    int k = beg;
    for (; k + 4 <= end; k += 4) {
        int s = csr_src[k + g];
        float4 vy = *reinterpret_cast<const float4*>(y + (long)s * HIDDEN + q * 4);
        acc.x += vy.x; acc.y += vy.y; acc.z += vy.z; acc.w += vy.w;
    }
    int rem = end - k;
    if (g < rem) {
        int s = csr_src[k + g];
        float4 vy = *reinterpret_cast<const float4*>(y + (long)s * HIDDEN + q * 4);
        acc.x += vy.x; acc.y += vy.y; acc.z += vy.z; acc.w += vy.w;
    }
    acc.x += __shfl_xor(acc.x, 16, 64); acc.y += __shfl_xor(acc.y, 16, 64);
    acc.z += __shfl_xor(acc.z, 16, 64); acc.w += __shfl_xor(acc.w, 16, 64);
    acc.x += __shfl_xor(acc.x, 32, 64); acc.y += __shfl_xor(acc.y, 32, 64);
    acc.z += __shfl_xor(acc.z, 32, 64); acc.w += __shfl_xor(acc.w, 32, 64);
    float c = c_dst[v];
    float4 b = *reinterpret_cast<const float4*>(b2 + q * 4);
    float4 ws = *reinterpret_cast<const float4*>(We + q * 4);
    float4 wd = *reinterpret_cast<const float4*>(We + HIDDEN + q * 4);
    float hx = fmaf(c, acc.x, b.x), hy = fmaf(c, acc.y, b.y);
    float hz = fmaf(c, acc.z, b.z), hw = fmaf(c, acc.w, b.w);
    float ps = hx * ws.x + hy * ws.y + hz * ws.z + hw * ws.w;
    float pd = hx * wd.x + hy * wd.y + hz * wd.z + hw * wd.w;
    // reduce within 16-lane group (garbage in slots g>0 never crosses in)
#pragma unroll
    for (int o = 1; o <= 8; o <<= 1) {
        ps += __shfl_xor(ps, o, 64);
        pd += __shfl_xor(pd, o, 64);
    }
    if (l == 0) {
        a_s[v] = ps;
        a_d[v] = pd;
    }
}

// --- out[e] = sigmoid(a_s[src] + a_d[dst] + efeat.Wf + be) ---
__global__ __launch_bounds__(256) void edge_out_kernel(const int* __restrict__ src,
                                                       const int* __restrict__ dst,
                                                       const float* __restrict__ efeat,
                                                       const float* __restrict__ We,
                                                       const float* __restrict__ be,
                                                       const float* __restrict__ a_s,
                                                       const float* __restrict__ a_d,
                                                       float* __restrict__ out) {
    int e = blockIdx.x * 256 + threadIdx.x;
    if (e >= N_EDGES) return;
    float logit = a_s[src[e]] + a_d[dst[e]]
                + efeat[(long)e * 3 + 0] * We[2 * HIDDEN + 0]
                + efeat[(long)e * 3 + 1] * We[2 * HIDDEN + 1]
                + efeat[(long)e * 3 + 2] * We[2 * HIDDEN + 2]
                + be[0];
    out[e] = 1.0f / (1.0f + expf(-logit));
}

extern "C" void kernel_launch(void* const* d_in, const int* in_sizes, int n_in,
                              void* d_out, int out_size, void* d_ws, size_t ws_size,
                              hipStream_t stream) {
    const float* x     = (const float*)d_in[0];
    const float* efeat = (const float*)d_in[1];
    const int*   src   = (const int*)d_in[2];
    const int*   dst   = (const int*)d_in[3];
    const float* W1    = (const float*)d_in[4];
    const float* b1    = (const float*)d_in[5];
    const float* W2    = (const float*)d_in[6];
    const float* b2    = (const float*)d_in[7];
    const float* We    = (const float*)d_in[8];
    const float* be    = (const float*)d_in[9];
    float* out = (float*)d_out;

    // 256B-aligned workspace carve-up (float4 paths require 16B alignment)
    char* p = (char*)d_ws;
    auto alloc = [&](size_t bytes) {
        char* r = p;
        p += (bytes + 255) & ~(size_t)255;
        return r;
    };
    float* c_src   = (float*)alloc((size_t)N_NODES * 4);
    float* c_dst   = (float*)alloc((size_t)N_NODES * 4);
    float* a_s     = (float*)alloc((size_t)N_NODES * 4);
    float* a_d     = (float*)alloc((size_t)N_NODES * 4);
    int*   degs    = (int*)alloc((size_t)3 * N_NODES * 4);  // deg_out | deg_in | cnt
    int*   offs    = (int*)alloc((size_t)(N_NODES + 1) * 4);
    int*   bsum    = (int*)alloc(64 * 4);
    int*   csr_src = (int*)alloc((size_t)N_EDGES * 4);
    float* bufA    = (float*)alloc((size_t)N_NODES * HIDDEN * 4);
    float* bufB    = (float*)alloc((size_t)N_NODES * HIDDEN * 4);
    int* deg_out = degs;
    int* deg_in  = degs + N_NODES;
    int* cnt     = degs + 2 * N_NODES;

    const int NB_SCAN = (N_NODES + SCAN_ELEMS - 1) / SCAN_ELEMS;  // 49

    // degrees -> c_src/c_dst ; CSR build
    hipMemsetAsync(degs, 0, (size_t)3 * N_NODES * 4, stream);
    deg_kernel<<<N_EDGES / 256, 256, 0, stream>>>(src, dst, deg_out, deg_in);
    cnorm_kernel<<<(N_NODES + 255) / 256, 256, 0, stream>>>(deg_out, deg_in, c_src, c_dst);
    scan1_kernel<<<NB_SCAN, SCAN_BLK, 0, stream>>>(deg_in, offs, bsum);
    scan2_kernel<<<1, 64, 0, stream>>>(bsum, NB_SCAN);
    scan3_kernel<<<(N_NODES + 255) / 256, 256, 0, stream>>>(offs, bsum);
    bucket_kernel<<<N_EDGES / 256, 256, 0, stream>>>(src, dst, offs, cnt, csr_src);

    // layer 1: y1 = (x*c_src)@W1 ; h1 = relu(c_dst * gather + b1)
    const int NT1 = (N_NODES + 31) / 32;  // 1563 tiles
    gemm_scaled_kernel<IN_FEATS><<<NT1, 256, 0, stream>>>(x, c_src, W1, bufA);
    gather_relu_kernel<<<N_NODES / 4, 256, 0, stream>>>(bufA, offs, csr_src, c_dst, b1, bufB);

    // layer 2: y2 = (h1*c_src)@W2 ; fused gather + bias + We-dot -> a_s/a_d
    gemm_scaled_kernel<HIDDEN><<<NT1, 256, 0, stream>>>(bufB, c_src, W2, bufA);
    gather_logit_kernel<<<N_NODES / 4, 256, 0, stream>>>(bufA, offs, csr_src, c_dst, b2, We, a_s, a_d);

    // edge output
    edge_out_kernel<<<N_EDGES / 256, 256, 0, stream>>>(src, dst, efeat, We, be, a_s, a_d, out);
}